// Round 1
// baseline (463.267 us; speedup 1.0000x reference)
//
#include <hip/hip_runtime.h>

#define LEAKY(v) ((v) >= 0.f ? (v) : 0.1f * (v))

constexpr int Q = 16384, S = 16384, KNN = 32, F = 64, O = 64;
constexpr int NEDGE = Q * KNN;          // 524288
constexpr int QB = 8;                   // q's per main block
constexpr int EB = QB * KNN;            // 256 edges per block
constexpr int GD = Q / QB;              // 2048 blocks
constexpr int NB0 = 64;                 // moments blocks
constexpr int EPAD = 260;               // padded edge dim (f-major LDS)
constexpr int OPAD = 68;                // padded o dim
constexpr float EPSV = 1e-5f;

// workspace byte offsets
constexpr size_t CNT_OFF  = 0;                                   // S ints (histogram)
constexpr size_t P0_OFF   = 66048;                               // NB0 * 4160 floats (Syy+Sy partials)
constexpr size_t ST0_OFF  = P0_OFF + (size_t)NB0 * 4160 * 4;     // 128 floats: scale0, shift0
constexpr size_t ZMIN_OFF = ST0_OFF + 512;                       // Q*O floats
constexpr size_t P1_OFF   = ZMIN_OFF + (size_t)Q * O * 4;        // GD * 128 floats (sum,sumsq partials)
constexpr size_t ST1_OFF  = P1_OFF + (size_t)GD * 128 * 4;       // 128 floats: scale1, shift1

// ---------------- histogram of neighbor indices (idx==S contributes zeros, skip) ----------
__global__ void k_hist(const int* __restrict__ inds, int* __restrict__ cnt) {
  int i = blockIdx.x * blockDim.x + threadIdx.x;
  int stride = gridDim.x * blockDim.x;
  for (; i < NEDGE; i += stride) {
    int idx = inds[i];
    if (idx < S) atomicAdd(&cnt[idx], 1);
  }
}

// ---------------- weighted moments of feat: Syy[f][g], Sy[f] (block partials) -------------
__global__ void k_moments(const float* __restrict__ feat, const int* __restrict__ cnt,
                          float* __restrict__ p0) {
  __shared__ float frow[4][64];
  __shared__ float scnt[4];
  const int t = threadIdx.x;
  const int b = blockIdx.x;
  const int s0 = b * (S / NB0);   // 256 s per block

  float acc[16];
#pragma unroll
  for (int j = 0; j < 16; ++j) acc[j] = 0.f;
  float accSy = 0.f;
  const int fr = t >> 2, gg0 = (t & 3) * 16;

  for (int s = s0; s < s0 + S / NB0; s += 4) {
    __syncthreads();
    frow[t >> 6][t & 63] = feat[(s + (t >> 6)) * F + (t & 63)];
    if (t < 4) scnt[t] = (float)cnt[s + t];
    __syncthreads();
#pragma unroll
    for (int u = 0; u < 4; ++u) {
      float fc = scnt[u];
      if (fc != 0.f) {
        float a = frow[u][fr] * fc;
#pragma unroll
        for (int j = 0; j < 16; ++j) acc[j] += a * frow[u][gg0 + j];
        if (t < F) accSy += frow[u][t] * fc;
      }
    }
  }
#pragma unroll
  for (int j = 0; j < 16; ++j) p0[(size_t)b * 4160 + t * 16 + j] = acc[j];
  if (t < F) p0[(size_t)b * 4160 + 4096 + t] = accSy;
}

// ---------------- reduce moments, compute BN0 scale/shift ---------------------------------
__global__ void k_stats0(const float* __restrict__ p0, const float* __restrict__ w0,
                         const float* __restrict__ gamma0, const float* __restrict__ beta0,
                         float* __restrict__ st0) {
  __shared__ __align__(16) float red[4160];
  const int t = threadIdx.x;
  for (int c = t; c < 4160; c += 256) {
    float s = 0.f;
    for (int b = 0; b < NB0; ++b) s += p0[(size_t)b * 4160 + c];
    red[c] = s;
  }
  __syncthreads();
  if (t < O) {
    float w[F];
#pragma unroll
    for (int f = 0; f < F; ++f) w[f] = w0[t * F + f];
    const float invN = 1.f / (float)NEDGE;
    float mean = 0.f;
#pragma unroll
    for (int f = 0; f < F; ++f) mean += w[f] * red[4096 + f];
    mean *= invN;
    float e2 = 0.f;
    for (int f = 0; f < F; ++f) {
      const float4* rp = reinterpret_cast<const float4*>(&red[f * 64]);
      float partial = 0.f;
#pragma unroll
      for (int g4 = 0; g4 < 16; ++g4) {
        float4 rv = rp[g4];
        partial += rv.x * w[g4 * 4] + rv.y * w[g4 * 4 + 1] + rv.z * w[g4 * 4 + 2] + rv.w * w[g4 * 4 + 3];
      }
      e2 += w[f] * partial;
    }
    e2 *= invN;
    float var = e2 - mean * mean;
    float sc = gamma0[t] * rsqrtf(var + EPSV);
    st0[t] = sc;
    st0[O + t] = beta0[t] - mean * sc;
  }
}

// ---------------- main pass: h -> bn0 -> leaky -> ker -> z; track max/min + sums ----------
__launch_bounds__(256, 1)
__global__ void k_main(const float* __restrict__ qpts, const float* __restrict__ spts,
                       const float* __restrict__ feat, const int* __restrict__ inds,
                       const float* __restrict__ w0g, const float* __restrict__ w1g,
                       const float* __restrict__ st0,
                       float* __restrict__ zmax, float* __restrict__ zmin,
                       float* __restrict__ p1) {
  __shared__ __align__(16) float buf[F * EPAD];         // Y (f-major), then Hb (o-major)
  __shared__ __align__(16) float w0t[F * OPAD];         // [f][o]
  __shared__ __align__(16) float w1r[3 * O * OPAD];     // [i][o'][o]
  __shared__ __align__(16) float xb[3 * EPAD];          // x per edge
  __shared__ float s0buf[O];
  __shared__ float sh0buf[O];
  __shared__ float swred[4][128];
  __shared__ int sidx[EB];

  const int t = threadIdx.x;
  const int blk = blockIdx.x;
  const int base = blk * EB;

  // stage weights (transposed for column-contiguous reads)
  for (int c = t; c < F * O; c += 256) {
    int o = c >> 6, f = c & 63;
    w0t[f * OPAD + o] = w0g[c];
  }
  for (int c = t; c < 3 * O * O; c += 256) {
    int row = c >> 6, op = c & 63;
    int o = row / 3;
    int i = row - 3 * o;
    w1r[(i * O + op) * OPAD + o] = w1g[c];
  }
  if (t < O) { s0buf[t] = st0[t]; sh0buf[t] = st0[O + t]; }

  // per-edge idx and relative xyz
  {
    int idx = inds[base + t];
    sidx[t] = idx;
    int q = blk * QB + (t >> 5);
    float x0 = 0.f, x1 = 0.f, x2 = 0.f;
    if (idx < S) {
      x0 = spts[idx * 3 + 0] - qpts[q * 3 + 0];
      x1 = spts[idx * 3 + 1] - qpts[q * 3 + 1];
      x2 = spts[idx * 3 + 2] - qpts[q * 3 + 2];
    }
    xb[0 * EPAD + t] = x0;
    xb[1 * EPAD + t] = x1;
    xb[2 * EPAD + t] = x2;
  }
  __syncthreads();

  // stage gathered features transposed: buf[f][e]
  {
    const int fo = (t & 3) * 16;
#pragma unroll
    for (int p = 0; p < 4; ++p) {
      int e = p * 64 + (t >> 2);
      int idx = sidx[e];
      if (idx < S) {
        const float4* src = reinterpret_cast<const float4*>(feat + (size_t)idx * F + fo);
#pragma unroll
        for (int v = 0; v < 4; ++v) {
          float4 d = src[v];
          buf[(fo + v * 4 + 0) * EPAD + e] = d.x;
          buf[(fo + v * 4 + 1) * EPAD + e] = d.y;
          buf[(fo + v * 4 + 2) * EPAD + e] = d.z;
          buf[(fo + v * 4 + 3) * EPAD + e] = d.w;
        }
      } else {
#pragma unroll
        for (int j = 0; j < 16; ++j) buf[(fo + j) * EPAD + e] = 0.f;
      }
    }
  }
  __syncthreads();

  const int ot = t & 7, et = t >> 3;
  const int o0 = ot * 8, e0 = et * 8;

  // Phase A: H = W0 * Y  (8x8 register tile per thread)
  float acc[8][8];
#pragma unroll
  for (int r = 0; r < 8; ++r)
#pragma unroll
    for (int c = 0; c < 8; ++c) acc[r][c] = 0.f;

  for (int f = 0; f < F; ++f) {
    float4 a0 = *reinterpret_cast<const float4*>(&w0t[f * OPAD + o0]);
    float4 a1 = *reinterpret_cast<const float4*>(&w0t[f * OPAD + o0 + 4]);
    float4 b0 = *reinterpret_cast<const float4*>(&buf[f * EPAD + e0]);
    float4 b1 = *reinterpret_cast<const float4*>(&buf[f * EPAD + e0 + 4]);
    float av[8] = {a0.x, a0.y, a0.z, a0.w, a1.x, a1.y, a1.z, a1.w};
    float bv[8] = {b0.x, b0.y, b0.z, b0.w, b1.x, b1.y, b1.z, b1.w};
#pragma unroll
    for (int c = 0; c < 8; ++c)
#pragma unroll
      for (int r = 0; r < 8; ++r) acc[r][c] += av[r] * bv[c];
  }

  // BN0 + leaky
#pragma unroll
  for (int r = 0; r < 8; ++r) {
    float sc = s0buf[o0 + r], sh = sh0buf[o0 + r];
#pragma unroll
    for (int c = 0; c < 8; ++c) {
      float v = acc[r][c] * sc + sh;
      acc[r][c] = LEAKY(v);
    }
  }
  __syncthreads();   // all reads of Y done before overwrite
#pragma unroll
  for (int r = 0; r < 8; ++r) {
    *reinterpret_cast<float4*>(&buf[(o0 + r) * EPAD + e0]) =
        make_float4(acc[r][0], acc[r][1], acc[r][2], acc[r][3]);
    *reinterpret_cast<float4*>(&buf[(o0 + r) * EPAD + e0 + 4]) =
        make_float4(acc[r][4], acc[r][5], acc[r][6], acc[r][7]);
  }
  __syncthreads();

  // Phase B: z[o,e] = sum_op sum_i W1[3o+i,op] * Hb[op,e] * x[i,e]
  float xr[3][8];
#pragma unroll
  for (int i = 0; i < 3; ++i) {
    float4 xa = *reinterpret_cast<const float4*>(&xb[i * EPAD + e0]);
    float4 xc = *reinterpret_cast<const float4*>(&xb[i * EPAD + e0 + 4]);
    xr[i][0] = xa.x; xr[i][1] = xa.y; xr[i][2] = xa.z; xr[i][3] = xa.w;
    xr[i][4] = xc.x; xr[i][5] = xc.y; xr[i][6] = xc.z; xr[i][7] = xc.w;
  }

  float z[8][8];
#pragma unroll
  for (int r = 0; r < 8; ++r)
#pragma unroll
    for (int c = 0; c < 8; ++c) z[r][c] = 0.f;

  for (int op = 0; op < O; ++op) {
    float4 b0 = *reinterpret_cast<const float4*>(&buf[op * EPAD + e0]);
    float4 b1 = *reinterpret_cast<const float4*>(&buf[op * EPAD + e0 + 4]);
    float bv[8] = {b0.x, b0.y, b0.z, b0.w, b1.x, b1.y, b1.z, b1.w};
#pragma unroll
    for (int i = 0; i < 3; ++i) {
      float4 a0 = *reinterpret_cast<const float4*>(&w1r[(i * O + op) * OPAD + o0]);
      float4 a1 = *reinterpret_cast<const float4*>(&w1r[(i * O + op) * OPAD + o0 + 4]);
      float av[8] = {a0.x, a0.y, a0.z, a0.w, a1.x, a1.y, a1.z, a1.w};
#pragma unroll
      for (int c = 0; c < 8; ++c) {
        float bx = bv[c] * xr[i][c];
#pragma unroll
        for (int r = 0; r < 8; ++r) z[r][c] += av[r] * bx;
      }
    }
  }

  // per-thread stats over its 8 edges (all within one q)
  float zmx[8], zmn[8], zs[8], zq[8];
#pragma unroll
  for (int r = 0; r < 8; ++r) {
    float v = z[r][0];
    float mx = v, mn = v, s = v, sq = v * v;
#pragma unroll
    for (int c = 1; c < 8; ++c) {
      float u = z[r][c];
      mx = fmaxf(mx, u); mn = fminf(mn, u); s += u; sq += u * u;
    }
    zmx[r] = mx; zmn[r] = mn; zs[r] = s; zq[r] = sq;
  }
  // combine the 4 threads covering the same (q, o-range): lanes differ by 8,16
#pragma unroll
  for (int r = 0; r < 8; ++r) {
    zmx[r] = fmaxf(zmx[r], __shfl_xor(zmx[r], 8));
    zmn[r] = fminf(zmn[r], __shfl_xor(zmn[r], 8));
    zs[r] += __shfl_xor(zs[r], 8);
    zq[r] += __shfl_xor(zq[r], 8);
  }
#pragma unroll
  for (int r = 0; r < 8; ++r) {
    zmx[r] = fmaxf(zmx[r], __shfl_xor(zmx[r], 16));
    zmn[r] = fminf(zmn[r], __shfl_xor(zmn[r], 16));
    zs[r] += __shfl_xor(zs[r], 16);
    zq[r] += __shfl_xor(zq[r], 16);
  }
  if (((t >> 3) & 3) == 0) {           // one writer per (q, o-range)
    int q = blk * QB + (t >> 5);
    float* zp = zmax + (size_t)q * O + o0;
    *reinterpret_cast<float4*>(zp)     = make_float4(zmx[0], zmx[1], zmx[2], zmx[3]);
    *reinterpret_cast<float4*>(zp + 4) = make_float4(zmx[4], zmx[5], zmx[6], zmx[7]);
    float* np = zmin + (size_t)q * O + o0;
    *reinterpret_cast<float4*>(np)     = make_float4(zmn[0], zmn[1], zmn[2], zmn[3]);
    *reinterpret_cast<float4*>(np + 4) = make_float4(zmn[4], zmn[5], zmn[6], zmn[7]);
  }
  // finish sums across the two q's in the wave
#pragma unroll
  for (int r = 0; r < 8; ++r) {
    zs[r] += __shfl_xor(zs[r], 32);
    zq[r] += __shfl_xor(zq[r], 32);
  }
  if ((t & 63) < 8) {
    int w = t >> 6;
#pragma unroll
    for (int r = 0; r < 8; ++r) {
      swred[w][o0 + r] = zs[r];
      swred[w][64 + o0 + r] = zq[r];
    }
  }
  __syncthreads();
  if (t < 128)
    p1[(size_t)blk * 128 + t] = swred[0][t] + swred[1][t] + swred[2][t] + swred[3][t];
}

// ---------------- reduce z stats -> BN1 scale/shift ---------------------------------------
__global__ void k_stats1(const float* __restrict__ p1, const float* __restrict__ gamma1,
                         const float* __restrict__ beta1, float* __restrict__ st1) {
  __shared__ float red[128];
  const int t = threadIdx.x;     // 128 threads
  float s = 0.f;
  for (int b = 0; b < GD; ++b) s += p1[(size_t)b * 128 + t];
  red[t] = s;
  __syncthreads();
  if (t < O) {
    const float invN = 1.f / (float)NEDGE;
    float mean = red[t] * invN;
    float var = red[64 + t] * invN - mean * mean;
    float sc = gamma1[t] * rsqrtf(var + EPSV);
    st1[t] = sc;
    st1[O + t] = beta1[t] - mean * sc;
  }
}

// ---------------- finalize: pick max/min by scale sign, affine + leaky --------------------
__global__ void k_final(const float* __restrict__ st1, const float* __restrict__ zmin,
                        float* __restrict__ out) {
  int i = blockIdx.x * blockDim.x + threadIdx.x;
  if (i < Q * O) {
    int o = i & 63;
    float sc = st1[o], sh = st1[O + o];
    float base = (sc >= 0.f) ? out[i] : zmin[i];   // out currently holds zmax
    float v = base * sc + sh;
    out[i] = LEAKY(v);
  }
}

extern "C" void kernel_launch(void* const* d_in, const int* in_sizes, int n_in,
                              void* d_out, int out_size, void* d_ws, size_t ws_size,
                              hipStream_t stream) {
  const float* qpts = (const float*)d_in[0];
  const float* spts = (const float*)d_in[1];
  const float* feat = (const float*)d_in[2];
  const int*   inds = (const int*)d_in[3];
  const float* w0   = (const float*)d_in[4];
  const float* g0   = (const float*)d_in[5];
  const float* b0   = (const float*)d_in[6];
  const float* w1   = (const float*)d_in[7];
  const float* g1   = (const float*)d_in[8];
  const float* b1   = (const float*)d_in[9];
  float* out = (float*)d_out;

  char* ws = (char*)d_ws;
  int*   cnt  = (int*)(ws + CNT_OFF);
  float* p0   = (float*)(ws + P0_OFF);
  float* st0  = (float*)(ws + ST0_OFF);
  float* zmin = (float*)(ws + ZMIN_OFF);
  float* p1   = (float*)(ws + P1_OFF);
  float* st1  = (float*)(ws + ST1_OFF);

  hipMemsetAsync(cnt, 0, (size_t)S * sizeof(int), stream);
  k_hist<<<512, 256, 0, stream>>>(inds, cnt);
  k_moments<<<NB0, 256, 0, stream>>>(feat, cnt, p0);
  k_stats0<<<1, 256, 0, stream>>>(p0, w0, g0, b0, st0);
  k_main<<<GD, 256, 0, stream>>>(qpts, spts, feat, inds, w0, w1, st0, out, zmin, p1);
  k_stats1<<<1, 128, 0, stream>>>(p1, g1, b1, st1);
  k_final<<<(Q * O) / 256, 256, 0, stream>>>(st1, zmin, out);
}

// Round 2
// 153.779 us; speedup vs baseline: 3.0125x; 3.0125x over previous
//
#include <hip/hip_runtime.h>
#include <hip/hip_bf16.h>

typedef __attribute__((ext_vector_type(8))) short bf16x8;
typedef __attribute__((ext_vector_type(4))) short bf16x4;
typedef __attribute__((ext_vector_type(4))) float f32x4;

#define LEAKY(v) ((v) >= 0.f ? (v) : 0.1f * (v))

constexpr int Q = 16384, S = 16384, KNN = 32, F = 64, O = 64;
constexpr int NEDGE = Q * KNN;
constexpr int QB = 8;                   // q's per main block
constexpr int EB = 256;                 // edges per block
constexpr int GD = Q / QB;              // 2048 main blocks
constexpr int NB0 = 64;                 // moments blocks
constexpr int FP = 72;                  // padded bf16 row (144B stride)
constexpr float EPSV = 1e-5f;

// workspace byte offsets
constexpr size_t CNT_OFF  = 0;                                    // S ints
constexpr size_t P0_OFF   = 65536;                                // 64*4160 f32
constexpr size_t RED0_OFF = P0_OFF + (size_t)NB0 * 4160 * 4;      // 4160 f32
constexpr size_t ST0_OFF  = RED0_OFF + 16640;                     // 128 f32
constexpr size_t ZMIN_OFF = ST0_OFF + 512;                        // Q*O f32
constexpr size_t P1_OFF   = ZMIN_OFF + (size_t)Q * O * 4;         // GD*128 f32
constexpr size_t ST1_OFF  = P1_OFF + (size_t)GD * 128 * 4;        // 128 f32
constexpr size_t W0F_OFF  = ST1_OFF + 512;                        // 8*64*8 bf16
constexpr size_t W1F_OFF  = W0F_OFF + 8192;                       // 24*64*8 bf16

__device__ __forceinline__ short f2bf(float f) {
  __hip_bfloat16 h = __float2bfloat16(f);
  short r; __builtin_memcpy(&r, &h, 2); return r;
}

// ---------------- histogram of neighbor indices ----------------
__global__ void k_hist(const int* __restrict__ inds, int* __restrict__ cnt) {
  int i = blockIdx.x * blockDim.x + threadIdx.x;
  int stride = gridDim.x * blockDim.x;
  for (; i < NEDGE; i += stride) {
    int idx = inds[i];
    if (idx < S) atomicAdd(&cnt[idx], 1);
  }
}

// ---------------- weight fragment prep (A/B operand layout) ----------------
// frag layout: lane l holds row/col = l&15, k = 8*(l>>4)+j (j=0..7 contiguous)
__global__ void k_prep(const float* __restrict__ w0g, const float* __restrict__ w1g,
                       short* __restrict__ w0f, short* __restrict__ w1f) {
  const int t = blockIdx.x * 256 + threadIdx.x;   // 2048 entries
  const int fa = t >> 6, ln = t & 63;
  const int l4 = ln >> 4, l15 = ln & 15;
  if (fa < 8) {
    // W0 A-operand frags: A[m=o][k=f]; frag (mt,kk): o=16mt+l15, f=32kk+8l4
    const int mt = fa >> 1, kk = fa & 1;
    const int o = 16 * mt + l15, f = 32 * kk + 8 * l4;
    const float* src = w0g + o * 64 + f;
    bf16x8 pk;
#pragma unroll
    for (int j = 0; j < 8; ++j) pk[j] = f2bf(src[j]);
    *(bf16x8*)&w0f[t * 8] = pk;
  } else {
    // W1 B-operand frags: B[k=op][n=c], c = i*64+o; frag nt=i*4+b: o=16b+l15, op=32kk+8l4
    const int fb = fa - 8;                 // 0..23
    const int nt = fb >> 1, kk = fb & 1;
    const int i = nt >> 2, b = nt & 3;
    const int o = 16 * b + l15, op = 32 * kk + 8 * l4;
    const float* src = w1g + (o * 3 + i) * 64 + op;
    bf16x8 pk;
#pragma unroll
    for (int j = 0; j < 8; ++j) pk[j] = f2bf(src[j]);
    *(bf16x8*)&w1f[(fb * 64 + ln) * 8] = pk;
  }
}

// ---------------- weighted moments of feat (fp32 exact) ----------------
__global__ void k_moments(const float* __restrict__ feat, const int* __restrict__ cnt,
                          float* __restrict__ p0) {
  __shared__ float frow[4][64];
  __shared__ float scnt[4];
  const int t = threadIdx.x;
  const int b = blockIdx.x;
  const int s0 = b * (S / NB0);

  float acc[16];
#pragma unroll
  for (int j = 0; j < 16; ++j) acc[j] = 0.f;
  float accSy = 0.f;
  const int fr = t >> 2, gg0 = (t & 3) * 16;

  for (int s = s0; s < s0 + S / NB0; s += 4) {
    __syncthreads();
    frow[t >> 6][t & 63] = feat[(s + (t >> 6)) * F + (t & 63)];
    if (t < 4) scnt[t] = (float)cnt[s + t];
    __syncthreads();
#pragma unroll
    for (int u = 0; u < 4; ++u) {
      float fc = scnt[u];
      if (fc != 0.f) {
        float a = frow[u][fr] * fc;
#pragma unroll
        for (int j = 0; j < 16; ++j) acc[j] += a * frow[u][gg0 + j];
        if (t < F) accSy += frow[u][t] * fc;
      }
    }
  }
#pragma unroll
  for (int j = 0; j < 16; ++j) p0[(size_t)b * 4160 + t * 16 + j] = acc[j];
  if (t < F) p0[(size_t)b * 4160 + 4096 + t] = accSy;
}

// ---------------- parallel reduce of moment partials ----------------
__global__ void k_red0(const float* __restrict__ p0, float* __restrict__ red0) {
  const int c = blockIdx.x * 256 + threadIdx.x;
  if (c < 4160) {
    float s = 0.f;
    for (int b = 0; b < NB0; ++b) s += p0[(size_t)b * 4160 + c];
    red0[c] = s;
  }
}

// ---------------- BN0 scale/shift from moments ----------------
__global__ void k_stats0(const float* __restrict__ red0, const float* __restrict__ w0g,
                         const float* __restrict__ g0, const float* __restrict__ b0,
                         float* __restrict__ st0) {
  __shared__ __align__(16) float red[4160];
  __shared__ float part[256];
  const int t = threadIdx.x;
  for (int c = t; c < 4160; c += 256) red[c] = red0[c];
  __syncthreads();
  const int o = t & 63, ch = t >> 6;
  float wB[64];
#pragma unroll
  for (int j4 = 0; j4 < 16; ++j4) {
    float4 w4 = *(const float4*)(w0g + o * 64 + 4 * j4);
    wB[4 * j4] = w4.x; wB[4 * j4 + 1] = w4.y; wB[4 * j4 + 2] = w4.z; wB[4 * j4 + 3] = w4.w;
  }
  float e2p = 0.f;
  for (int f = ch * 16; f < ch * 16 + 16; ++f) {
    const float4* rp = (const float4*)&red[f * 64];
    float partial = 0.f;
#pragma unroll
    for (int g4 = 0; g4 < 16; ++g4) {
      float4 rv = rp[g4];
      partial += rv.x * wB[4 * g4] + rv.y * wB[4 * g4 + 1] + rv.z * wB[4 * g4 + 2] + rv.w * wB[4 * g4 + 3];
    }
    e2p += wB[f] * partial;
  }
  part[t] = e2p;
  __syncthreads();
  if (t < 64) {
    float e2 = part[t] + part[t + 64] + part[t + 128] + part[t + 192];
    float mean = 0.f;
    for (int f = 0; f < 64; ++f) mean += wB[f] * red[4096 + f];
    const float invN = 1.f / (float)NEDGE;
    mean *= invN; e2 *= invN;
    float var = e2 - mean * mean;
    float sc = g0[t] * rsqrtf(var + EPSV);
    st0[t] = sc;
    st0[O + t] = b0[t] - mean * sc;
  }
}

// ---------------- main MFMA pass ----------------
__launch_bounds__(256, 2)
__global__ void k_main(const float* __restrict__ qpts, const float* __restrict__ spts,
                       const float* __restrict__ feat, const int* __restrict__ inds,
                       const short* __restrict__ w0f, const short* __restrict__ w1f,
                       const float* __restrict__ st0,
                       float* __restrict__ zmax, float* __restrict__ zmin,
                       float* __restrict__ p1) {
  __shared__ __align__(16) short ybuf[EB * FP];   // Y then H in place, [e][72] bf16
  __shared__ __align__(16) float xb[3 * EB];
  __shared__ float swred[4][128];

  const int t = threadIdx.x, blk = blockIdx.x;
  const int wv = t >> 6, ln = t & 63, l4 = ln >> 4, l15 = ln & 15;

  // ---- stage per-edge data (each wave stages & consumes its own 64 rows)
  {
    const int e = t;
    const int idx = inds[(size_t)blk * EB + e];
    const int q = blk * QB + (e >> 5);
    float x0 = 0.f, x1 = 0.f, x2 = 0.f;
    if (idx < S) {
      x0 = spts[idx * 3 + 0] - qpts[q * 3 + 0];
      x1 = spts[idx * 3 + 1] - qpts[q * 3 + 1];
      x2 = spts[idx * 3 + 2] - qpts[q * 3 + 2];
      const float4* fr = (const float4*)(feat + (size_t)idx * F);
#pragma unroll
      for (int c = 0; c < 8; ++c) {
        float4 a = fr[2 * c], b = fr[2 * c + 1];
        bf16x8 pk;
        pk[0] = f2bf(a.x); pk[1] = f2bf(a.y); pk[2] = f2bf(a.z); pk[3] = f2bf(a.w);
        pk[4] = f2bf(b.x); pk[5] = f2bf(b.y); pk[6] = f2bf(b.z); pk[7] = f2bf(b.w);
        *(bf16x8*)&ybuf[e * FP + 8 * c] = pk;
      }
    } else {
      bf16x8 pk;
#pragma unroll
      for (int j = 0; j < 8; ++j) pk[j] = 0;
#pragma unroll
      for (int c = 0; c < 8; ++c) *(bf16x8*)&ybuf[e * FP + 8 * c] = pk;
    }
    xb[0 * EB + e] = x0; xb[1 * EB + e] = x1; xb[2 * EB + e] = x2;
  }

  // BN0 scale/shift regs: o = 16mt + 4*l4 + r
  float scr[4][4], shr[4][4];
#pragma unroll
  for (int mt = 0; mt < 4; ++mt)
#pragma unroll
    for (int r = 0; r < 4; ++r) {
      int o = 16 * mt + 4 * l4 + r;
      scr[mt][r] = st0[o]; shr[mt][r] = st0[O + o];
    }

  // W0 A-frags (global, L2-hot, coalesced)
  const bf16x8* w0v = (const bf16x8*)w0f;
  bf16x8 w0a[8];
#pragma unroll
  for (int fa = 0; fa < 8; ++fa) w0a[fa] = w0v[fa * 64 + ln];

  __syncthreads();

  // ---- Phase A: D1[o][e] = W0 * Y ; BN0+leaky ; write H over Y
#pragma unroll
  for (int nt = 0; nt < 4; ++nt) {
    const int erow = wv * 64 + nt * 16 + l15;
    bf16x8 y0 = *(const bf16x8*)&ybuf[erow * FP + 8 * l4];        // f = 8*l4..+7
    bf16x8 y1 = *(const bf16x8*)&ybuf[erow * FP + 32 + 8 * l4];   // f = 32+8*l4..+7
#pragma unroll
    for (int mt = 0; mt < 4; ++mt) {
      f32x4 acc = {0.f, 0.f, 0.f, 0.f};
      acc = __builtin_amdgcn_mfma_f32_16x16x32_bf16(w0a[2 * mt], y0, acc, 0, 0, 0);
      acc = __builtin_amdgcn_mfma_f32_16x16x32_bf16(w0a[2 * mt + 1], y1, acc, 0, 0, 0);
      bf16x4 hv;
#pragma unroll
      for (int r = 0; r < 4; ++r) {
        float v = acc[r] * scr[mt][r] + shr[mt][r];
        v = LEAKY(v);
        hv[r] = f2bf(v);
      }
      // H[e = erow][o = 16mt+4l4 .. +3]  (8B packed)
      *(bf16x4*)&ybuf[erow * FP + 16 * mt + 4 * l4] = hv;
    }
  }

  // ---- Phase B operand prefetch (H rows + x vectors, all wave-local)
  bf16x8 hA[4][2];
  f32x4 xv[4][3];
#pragma unroll
  for (int mt = 0; mt < 4; ++mt) {
    const int erow = wv * 64 + mt * 16 + l15;
    hA[mt][0] = *(const bf16x8*)&ybuf[erow * FP + 8 * l4];
    hA[mt][1] = *(const bf16x8*)&ybuf[erow * FP + 32 + 8 * l4];
    const int ex = wv * 64 + mt * 16 + 4 * l4;
#pragma unroll
    for (int i = 0; i < 3; ++i) xv[mt][i] = *(const f32x4*)&xb[i * EB + ex];
  }

  const bf16x8* w1v = (const bf16x8*)w1f;
  float zmx[2][4], zmn[2][4], zs[4], zq[4];
#pragma unroll
  for (int j = 0; j < 4; ++j) {
    zs[j] = 0.f; zq[j] = 0.f;
    zmx[0][j] = -3.4e38f; zmx[1][j] = -3.4e38f;
    zmn[0][j] = 3.4e38f;  zmn[1][j] = 3.4e38f;
  }

  // ---- Phase B: D2[e][c=i*64+o] = H * W1p ; combine with x ; stats
#pragma unroll
  for (int b = 0; b < 4; ++b) {
    bf16x8 w1b[6];
#pragma unroll
    for (int i = 0; i < 3; ++i)
#pragma unroll
      for (int kk = 0; kk < 2; ++kk)
        w1b[i * 2 + kk] = w1v[(((i * 4 + b) * 2) + kk) * 64 + ln];
#pragma unroll
    for (int mt = 0; mt < 4; ++mt) {
      f32x4 z4 = {0.f, 0.f, 0.f, 0.f};
#pragma unroll
      for (int i = 0; i < 3; ++i) {
        f32x4 acc = {0.f, 0.f, 0.f, 0.f};
        acc = __builtin_amdgcn_mfma_f32_16x16x32_bf16(hA[mt][0], w1b[2 * i], acc, 0, 0, 0);
        acc = __builtin_amdgcn_mfma_f32_16x16x32_bf16(hA[mt][1], w1b[2 * i + 1], acc, 0, 0, 0);
#pragma unroll
        for (int r = 0; r < 4; ++r) z4[r] += acc[r] * xv[mt][i][r];
      }
      const int qh = mt >> 1;
#pragma unroll
      for (int r = 0; r < 4; ++r) {
        float v = z4[r];
        zmx[qh][b] = fmaxf(zmx[qh][b], v);
        zmn[qh][b] = fminf(zmn[qh][b], v);
        zs[b] += v; zq[b] += v * v;
      }
    }
  }

  // ---- cross-group (l4) reductions: lanes l, l^16, l^32 share o
#pragma unroll
  for (int qh = 0; qh < 2; ++qh)
#pragma unroll
    for (int b = 0; b < 4; ++b) {
      float m = zmx[qh][b];
      m = fmaxf(m, __shfl_xor(m, 16)); m = fmaxf(m, __shfl_xor(m, 32));
      zmx[qh][b] = m;
      float n = zmn[qh][b];
      n = fminf(n, __shfl_xor(n, 16)); n = fminf(n, __shfl_xor(n, 32));
      zmn[qh][b] = n;
    }
#pragma unroll
  for (int b = 0; b < 4; ++b) {
    float s = zs[b];  s += __shfl_xor(s, 16);  s += __shfl_xor(s, 32);  zs[b] = s;
    float sq = zq[b]; sq += __shfl_xor(sq, 16); sq += __shfl_xor(sq, 32); zq[b] = sq;
  }

  if (l4 == 0) {
#pragma unroll
    for (int qh = 0; qh < 2; ++qh) {
      const int q = blk * QB + wv * 2 + qh;
#pragma unroll
      for (int b = 0; b < 4; ++b) {
        zmax[(size_t)q * O + 16 * b + l15] = zmx[qh][b];
        zmin[(size_t)q * O + 16 * b + l15] = zmn[qh][b];
      }
    }
#pragma unroll
    for (int b = 0; b < 4; ++b) {
      swred[wv][16 * b + l15] = zs[b];
      swred[wv][64 + 16 * b + l15] = zq[b];
    }
  }
  __syncthreads();
  if (t < 128)
    p1[(size_t)blk * 128 + t] = swred[0][t] + swred[1][t] + swred[2][t] + swred[3][t];
}

// ---------------- reduce z stats + BN1 scale/shift (fused) ----------------
__global__ void k_red1(const float* __restrict__ p1, const float* __restrict__ g1,
                       const float* __restrict__ b1, float* __restrict__ st1) {
  __shared__ float rs[256], rq[256];
  const int o = blockIdx.x, t = threadIdx.x;
  float s = 0.f, q = 0.f;
  for (int r = t; r < GD; r += 256) {
    s += p1[(size_t)r * 128 + o];
    q += p1[(size_t)r * 128 + 64 + o];
  }
  rs[t] = s; rq[t] = q;
  __syncthreads();
  for (int off = 128; off > 0; off >>= 1) {
    if (t < off) { rs[t] += rs[t + off]; rq[t] += rq[t + off]; }
    __syncthreads();
  }
  if (t == 0) {
    const float invN = 1.f / (float)NEDGE;
    float mean = rs[0] * invN;
    float var = rq[0] * invN - mean * mean;
    float sc = g1[o] * rsqrtf(var + EPSV);
    st1[o] = sc;
    st1[O + o] = b1[o] - mean * sc;
  }
}

// ---------------- finalize: pick max/min by scale sign, affine + leaky ----------------
__global__ void k_final(const float* __restrict__ st1, const float* __restrict__ zmin,
                        float* __restrict__ out) {
  int i = blockIdx.x * blockDim.x + threadIdx.x;
  if (i < Q * O) {
    int o = i & 63;
    float sc = st1[o], sh = st1[O + o];
    float base = (sc >= 0.f) ? out[i] : zmin[i];   // out currently holds zmax
    float v = base * sc + sh;
    out[i] = LEAKY(v);
  }
}

extern "C" void kernel_launch(void* const* d_in, const int* in_sizes, int n_in,
                              void* d_out, int out_size, void* d_ws, size_t ws_size,
                              hipStream_t stream) {
  const float* qpts = (const float*)d_in[0];
  const float* spts = (const float*)d_in[1];
  const float* feat = (const float*)d_in[2];
  const int*   inds = (const int*)d_in[3];
  const float* w0   = (const float*)d_in[4];
  const float* g0   = (const float*)d_in[5];
  const float* b0   = (const float*)d_in[6];
  const float* w1   = (const float*)d_in[7];
  const float* g1   = (const float*)d_in[8];
  const float* b1   = (const float*)d_in[9];
  float* out = (float*)d_out;

  char* ws = (char*)d_ws;
  int*   cnt  = (int*)(ws + CNT_OFF);
  float* p0   = (float*)(ws + P0_OFF);
  float* red0 = (float*)(ws + RED0_OFF);
  float* st0  = (float*)(ws + ST0_OFF);
  float* zmin = (float*)(ws + ZMIN_OFF);
  float* p1   = (float*)(ws + P1_OFF);
  float* st1  = (float*)(ws + ST1_OFF);
  short* w0f  = (short*)(ws + W0F_OFF);
  short* w1f  = (short*)(ws + W1F_OFF);

  hipMemsetAsync(cnt, 0, (size_t)S * sizeof(int), stream);
  k_prep<<<8, 256, 0, stream>>>(w0, w1, w0f, w1f);
  k_hist<<<512, 256, 0, stream>>>(inds, cnt);
  k_moments<<<NB0, 256, 0, stream>>>(feat, cnt, p0);
  k_red0<<<17, 256, 0, stream>>>(p0, red0);
  k_stats0<<<1, 256, 0, stream>>>(red0, w0, g0, b0, st0);
  k_main<<<GD, 256, 0, stream>>>(qpts, spts, feat, inds, w0f, w1f, st0, out, zmin, p1);
  k_red1<<<64, 256, 0, stream>>>(p1, g1, b1, st1);
  k_final<<<(Q * O) / 256, 256, 0, stream>>>(st1, zmin, out);
}

// Round 3
// 89.492 us; speedup vs baseline: 5.1766x; 1.7184x over previous
//
#include <hip/hip_runtime.h>
#include <hip/hip_bf16.h>

typedef __attribute__((ext_vector_type(8))) short bf16x8;
typedef __attribute__((ext_vector_type(4))) short bf16x4;
typedef __attribute__((ext_vector_type(4))) float f32x4;

#define LEAKY(v) ((v) >= 0.f ? (v) : 0.1f * (v))

constexpr int Q = 16384, S = 16384, KNN = 32, F = 64, O = 64;
constexpr int NEDGE = Q * KNN;
constexpr int QB = 8;                   // q's per main block
constexpr int EB = 256;                 // edges per block
constexpr int GD = Q / QB;              // 2048 main blocks
constexpr int GH = 128;                 // k_hsq blocks (128 s each)
constexpr int FP = 72;                  // padded bf16 row (144B stride)
constexpr float EPSV = 1e-5f;

// workspace byte offsets
constexpr size_t CNT_OFF  = 0;                                    // S ints
constexpr size_t P0_OFF   = 65536;                                // GH*128 f32
constexpr size_t ST0_OFF  = P0_OFF + (size_t)GH * 128 * 4;        // 128 f32
constexpr size_t ZMIN_OFF = ST0_OFF + 512;                        // Q*O f32
constexpr size_t P1_OFF   = ZMIN_OFF + (size_t)Q * O * 4;         // GD*128 f32
constexpr size_t ST1_OFF  = P1_OFF + (size_t)GD * 128 * 4;        // 128 f32
constexpr size_t W0F_OFF  = ST1_OFF + 512;                        // 8*64*8 bf16
constexpr size_t W1F_OFF  = W0F_OFF + 8192;                       // 24*64*8 bf16

__device__ __forceinline__ short f2bf(float f) {
  __hip_bfloat16 h = __float2bfloat16(f);
  short r; __builtin_memcpy(&r, &h, 2); return r;
}

// ---------------- histogram of neighbor indices ----------------
__global__ void k_hist(const int* __restrict__ inds, int* __restrict__ cnt) {
  int i = blockIdx.x * blockDim.x + threadIdx.x;
  int stride = gridDim.x * blockDim.x;
  for (; i < NEDGE; i += stride) {
    int idx = inds[i];
    if (idx < S) atomicAdd(&cnt[idx], 1);
  }
}

// ---------------- weight fragment prep (A/B operand layout) ----------------
// frag layout: lane l holds row/col = l&15, k = 8*(l>>4)+j (j=0..7 contiguous)
__global__ void k_prep(const float* __restrict__ w0g, const float* __restrict__ w1g,
                       short* __restrict__ w0f, short* __restrict__ w1f) {
  const int t = blockIdx.x * 256 + threadIdx.x;   // 2048 entries
  const int fa = t >> 6, ln = t & 63;
  const int l4 = ln >> 4, l15 = ln & 15;
  if (fa < 8) {
    // W0 A-operand frags: A[m=o][k=f]; frag (mt,kk): o=16mt+l15, f=32kk+8l4
    const int mt = fa >> 1, kk = fa & 1;
    const int o = 16 * mt + l15, f = 32 * kk + 8 * l4;
    const float* src = w0g + o * 64 + f;
    bf16x8 pk;
#pragma unroll
    for (int j = 0; j < 8; ++j) pk[j] = f2bf(src[j]);
    *(bf16x8*)&w0f[t * 8] = pk;
  } else {
    // W1 B-operand frags: B[k=op][n=c], c = i*64+o; frag nt=i*4+b: o=16b+l15, op=32kk+8l4
    const int fb = fa - 8;                 // 0..23
    const int nt = fb >> 1, kk = fb & 1;
    const int i = nt >> 2, b = nt & 3;
    const int o = 16 * b + l15, op = 32 * kk + 8 * l4;
    const float* src = w1g + (o * 3 + i) * 64 + op;
    bf16x8 pk;
#pragma unroll
    for (int j = 0; j < 8; ++j) pk[j] = f2bf(src[j]);
    *(bf16x8*)&w1f[(fb * 64 + ln) * 8] = pk;
  }
}

// ---------------- BN0 stats via MFMA: sum cnt*h, cnt*h^2 (h bitwise == k_main's) --------
__global__ void k_hsq(const float* __restrict__ feat, const int* __restrict__ cnt,
                      const short* __restrict__ w0f, float* __restrict__ p0) {
  __shared__ float sred[4][2][64];
  const int t = threadIdx.x, blk = blockIdx.x;
  const int wv = t >> 6, ln = t & 63, l4 = ln >> 4, l15 = ln & 15;

  const bf16x8* w0v = (const bf16x8*)w0f;
  bf16x8 w0a[8];
#pragma unroll
  for (int fa = 0; fa < 8; ++fa) w0a[fa] = w0v[fa * 64 + ln];

  float hs[4][4], hq[4][4];
#pragma unroll
  for (int mt = 0; mt < 4; ++mt)
#pragma unroll
    for (int r = 0; r < 4; ++r) { hs[mt][r] = 0.f; hq[mt][r] = 0.f; }

#pragma unroll
  for (int tile = 0; tile < 2; ++tile) {
    const int s0 = blk * 128 + (wv * 2 + tile) * 16;
    const float wc = (float)cnt[s0 + l15];
    const float4* fr = (const float4*)(feat + (size_t)(s0 + l15) * 64);
    float4 a = fr[2 * l4], b = fr[2 * l4 + 1];
    float4 c = fr[8 + 2 * l4], d = fr[9 + 2 * l4];
    bf16x8 y0, y1;
    y0[0] = f2bf(a.x); y0[1] = f2bf(a.y); y0[2] = f2bf(a.z); y0[3] = f2bf(a.w);
    y0[4] = f2bf(b.x); y0[5] = f2bf(b.y); y0[6] = f2bf(b.z); y0[7] = f2bf(b.w);
    y1[0] = f2bf(c.x); y1[1] = f2bf(c.y); y1[2] = f2bf(c.z); y1[3] = f2bf(c.w);
    y1[4] = f2bf(d.x); y1[5] = f2bf(d.y); y1[6] = f2bf(d.z); y1[7] = f2bf(d.w);
#pragma unroll
    for (int mt = 0; mt < 4; ++mt) {
      f32x4 acc = {0.f, 0.f, 0.f, 0.f};
      acc = __builtin_amdgcn_mfma_f32_16x16x32_bf16(w0a[2 * mt], y0, acc, 0, 0, 0);
      acc = __builtin_amdgcn_mfma_f32_16x16x32_bf16(w0a[2 * mt + 1], y1, acc, 0, 0, 0);
#pragma unroll
      for (int r = 0; r < 4; ++r) {
        float h = acc[r];
        hs[mt][r] += wc * h;
        hq[mt][r] += wc * h * h;
      }
    }
  }
  // reduce over the 16 s-columns (lanes differing in l15 bits)
#pragma unroll
  for (int mt = 0; mt < 4; ++mt)
#pragma unroll
    for (int r = 0; r < 4; ++r) {
      float s = hs[mt][r], q = hq[mt][r];
#pragma unroll
      for (int d = 1; d < 16; d <<= 1) { s += __shfl_xor(s, d); q += __shfl_xor(q, d); }
      hs[mt][r] = s; hq[mt][r] = q;
    }
  if (l15 == 0) {
#pragma unroll
    for (int mt = 0; mt < 4; ++mt)
#pragma unroll
      for (int r = 0; r < 4; ++r) {
        const int o = 16 * mt + 4 * l4 + r;
        sred[wv][0][o] = hs[mt][r];
        sred[wv][1][o] = hq[mt][r];
      }
  }
  __syncthreads();
  if (t < 128) {
    const int qq = t >> 6, o = t & 63;
    p0[(size_t)blk * 128 + t] =
        sred[0][qq][o] + sred[1][qq][o] + sred[2][qq][o] + sred[3][qq][o];
  }
}

// ---------------- reduce partials -> BN0 scale/shift ----------------
__global__ void k_stats0(const float* __restrict__ p0, const float* __restrict__ g0,
                         const float* __restrict__ b0, float* __restrict__ st0) {
  const int t = threadIdx.x;    // 64 threads
  if (t < O) {
    float s = 0.f, q = 0.f;
    for (int b = 0; b < GH; ++b) {
      s += p0[(size_t)b * 128 + t];
      q += p0[(size_t)b * 128 + 64 + t];
    }
    const float invN = 1.f / (float)NEDGE;
    float mean = s * invN;
    float var = q * invN - mean * mean;
    float sc = g0[t] * rsqrtf(var + EPSV);
    st0[t] = sc;
    st0[O + t] = b0[t] - mean * sc;
  }
}

// ---------------- main MFMA pass ----------------
__launch_bounds__(256, 3)
__global__ void k_main(const float* __restrict__ qpts, const float* __restrict__ spts,
                       const float* __restrict__ feat, const int* __restrict__ inds,
                       const short* __restrict__ w0f, const short* __restrict__ w1f,
                       const float* __restrict__ st0,
                       float* __restrict__ zmax, float* __restrict__ zmin,
                       float* __restrict__ p1) {
  __shared__ __align__(16) short ybuf[EB * FP];   // Y then H in place, [e][72] bf16
  __shared__ __align__(16) float xb[3 * EB];
  __shared__ float swred[4][128];

  const int t = threadIdx.x, blk = blockIdx.x;
  const int wv = t >> 6, ln = t & 63, l4 = ln >> 4, l15 = ln & 15;

  // ---- stage per-edge data (each wave stages & consumes its own 64 rows)
  {
    const int e = t;
    const int idx = inds[(size_t)blk * EB + e];
    const int q = blk * QB + (e >> 5);
    float x0 = 0.f, x1 = 0.f, x2 = 0.f;
    if (idx < S) {
      x0 = spts[idx * 3 + 0] - qpts[q * 3 + 0];
      x1 = spts[idx * 3 + 1] - qpts[q * 3 + 1];
      x2 = spts[idx * 3 + 2] - qpts[q * 3 + 2];
      const float4* fr = (const float4*)(feat + (size_t)idx * F);
#pragma unroll
      for (int c = 0; c < 8; ++c) {
        float4 a = fr[2 * c], b = fr[2 * c + 1];
        bf16x8 pk;
        pk[0] = f2bf(a.x); pk[1] = f2bf(a.y); pk[2] = f2bf(a.z); pk[3] = f2bf(a.w);
        pk[4] = f2bf(b.x); pk[5] = f2bf(b.y); pk[6] = f2bf(b.z); pk[7] = f2bf(b.w);
        *(bf16x8*)&ybuf[e * FP + 8 * c] = pk;
      }
    } else {
      bf16x8 pk;
#pragma unroll
      for (int j = 0; j < 8; ++j) pk[j] = 0;
#pragma unroll
      for (int c = 0; c < 8; ++c) *(bf16x8*)&ybuf[e * FP + 8 * c] = pk;
    }
    xb[0 * EB + e] = x0; xb[1 * EB + e] = x1; xb[2 * EB + e] = x2;
  }

  // BN0 scale/shift regs: o = 16mt + 4*l4 + r
  float scr[4][4], shr[4][4];
#pragma unroll
  for (int mt = 0; mt < 4; ++mt)
#pragma unroll
    for (int r = 0; r < 4; ++r) {
      int o = 16 * mt + 4 * l4 + r;
      scr[mt][r] = st0[o]; shr[mt][r] = st0[O + o];
    }

  // W0 A-frags (global, L2-hot, coalesced)
  const bf16x8* w0v = (const bf16x8*)w0f;
  bf16x8 w0a[8];
#pragma unroll
  for (int fa = 0; fa < 8; ++fa) w0a[fa] = w0v[fa * 64 + ln];

  __syncthreads();

  // ---- Phase A: D1[o][e] = W0 * Y ; BN0+leaky ; write H over Y
#pragma unroll
  for (int nt = 0; nt < 4; ++nt) {
    const int erow = wv * 64 + nt * 16 + l15;
    bf16x8 y0 = *(const bf16x8*)&ybuf[erow * FP + 8 * l4];        // f = 8*l4..+7
    bf16x8 y1 = *(const bf16x8*)&ybuf[erow * FP + 32 + 8 * l4];   // f = 32+8*l4..+7
#pragma unroll
    for (int mt = 0; mt < 4; ++mt) {
      f32x4 acc = {0.f, 0.f, 0.f, 0.f};
      acc = __builtin_amdgcn_mfma_f32_16x16x32_bf16(w0a[2 * mt], y0, acc, 0, 0, 0);
      acc = __builtin_amdgcn_mfma_f32_16x16x32_bf16(w0a[2 * mt + 1], y1, acc, 0, 0, 0);
      bf16x4 hv;
#pragma unroll
      for (int r = 0; r < 4; ++r) {
        float v = acc[r] * scr[mt][r] + shr[mt][r];
        v = LEAKY(v);
        hv[r] = f2bf(v);
      }
      // H[e = erow][o = 16mt+4l4 .. +3]  (8B packed)
      *(bf16x4*)&ybuf[erow * FP + 16 * mt + 4 * l4] = hv;
    }
  }

  // ---- Phase B operand prefetch (H rows + x vectors, all wave-local)
  bf16x8 hA[4][2];
  f32x4 xv[4][3];
#pragma unroll
  for (int mt = 0; mt < 4; ++mt) {
    const int erow = wv * 64 + mt * 16 + l15;
    hA[mt][0] = *(const bf16x8*)&ybuf[erow * FP + 8 * l4];
    hA[mt][1] = *(const bf16x8*)&ybuf[erow * FP + 32 + 8 * l4];
    const int ex = wv * 64 + mt * 16 + 4 * l4;
#pragma unroll
    for (int i = 0; i < 3; ++i) xv[mt][i] = *(const f32x4*)&xb[i * EB + ex];
  }

  const bf16x8* w1v = (const bf16x8*)w1f;
  float zmx[2][4], zmn[2][4], zs[4], zq[4];
#pragma unroll
  for (int j = 0; j < 4; ++j) {
    zs[j] = 0.f; zq[j] = 0.f;
    zmx[0][j] = -3.4e38f; zmx[1][j] = -3.4e38f;
    zmn[0][j] = 3.4e38f;  zmn[1][j] = 3.4e38f;
  }

  // ---- Phase B: D2[e][c=i*64+o] = H * W1p ; combine with x ; stats
#pragma unroll
  for (int b = 0; b < 4; ++b) {
    bf16x8 w1b[6];
#pragma unroll
    for (int i = 0; i < 3; ++i)
#pragma unroll
      for (int kk = 0; kk < 2; ++kk)
        w1b[i * 2 + kk] = w1v[(((i * 4 + b) * 2) + kk) * 64 + ln];
#pragma unroll
    for (int mt = 0; mt < 4; ++mt) {
      f32x4 z4 = {0.f, 0.f, 0.f, 0.f};
#pragma unroll
      for (int i = 0; i < 3; ++i) {
        f32x4 acc = {0.f, 0.f, 0.f, 0.f};
        acc = __builtin_amdgcn_mfma_f32_16x16x32_bf16(hA[mt][0], w1b[2 * i], acc, 0, 0, 0);
        acc = __builtin_amdgcn_mfma_f32_16x16x32_bf16(hA[mt][1], w1b[2 * i + 1], acc, 0, 0, 0);
#pragma unroll
        for (int r = 0; r < 4; ++r) z4[r] += acc[r] * xv[mt][i][r];
      }
      const int qh = mt >> 1;
#pragma unroll
      for (int r = 0; r < 4; ++r) {
        float v = z4[r];
        zmx[qh][b] = fmaxf(zmx[qh][b], v);
        zmn[qh][b] = fminf(zmn[qh][b], v);
        zs[b] += v; zq[b] += v * v;
      }
    }
  }

  // ---- cross-group (l4) reductions: lanes l, l^16, l^32 share o
#pragma unroll
  for (int qh = 0; qh < 2; ++qh)
#pragma unroll
    for (int b = 0; b < 4; ++b) {
      float m = zmx[qh][b];
      m = fmaxf(m, __shfl_xor(m, 16)); m = fmaxf(m, __shfl_xor(m, 32));
      zmx[qh][b] = m;
      float n = zmn[qh][b];
      n = fminf(n, __shfl_xor(n, 16)); n = fminf(n, __shfl_xor(n, 32));
      zmn[qh][b] = n;
    }
#pragma unroll
  for (int b = 0; b < 4; ++b) {
    float s = zs[b];  s += __shfl_xor(s, 16);  s += __shfl_xor(s, 32);  zs[b] = s;
    float sq = zq[b]; sq += __shfl_xor(sq, 16); sq += __shfl_xor(sq, 32); zq[b] = sq;
  }

  if (l4 == 0) {
#pragma unroll
    for (int qh = 0; qh < 2; ++qh) {
      const int q = blk * QB + wv * 2 + qh;
#pragma unroll
      for (int b = 0; b < 4; ++b) {
        zmax[(size_t)q * O + 16 * b + l15] = zmx[qh][b];
        zmin[(size_t)q * O + 16 * b + l15] = zmn[qh][b];
      }
    }
#pragma unroll
    for (int b = 0; b < 4; ++b) {
      swred[wv][16 * b + l15] = zs[b];
      swred[wv][64 + 16 * b + l15] = zq[b];
    }
  }
  __syncthreads();
  if (t < 128)
    p1[(size_t)blk * 128 + t] = swred[0][t] + swred[1][t] + swred[2][t] + swred[3][t];
}

// ---------------- reduce z stats + BN1 scale/shift (fused) ----------------
__global__ void k_red1(const float* __restrict__ p1, const float* __restrict__ g1,
                       const float* __restrict__ b1, float* __restrict__ st1) {
  __shared__ float rs[256], rq[256];
  const int o = blockIdx.x, t = threadIdx.x;
  float s = 0.f, q = 0.f;
  for (int r = t; r < GD; r += 256) {
    s += p1[(size_t)r * 128 + o];
    q += p1[(size_t)r * 128 + 64 + o];
  }
  rs[t] = s; rq[t] = q;
  __syncthreads();
  for (int off = 128; off > 0; off >>= 1) {
    if (t < off) { rs[t] += rs[t + off]; rq[t] += rq[t + off]; }
    __syncthreads();
  }
  if (t == 0) {
    const float invN = 1.f / (float)NEDGE;
    float mean = rs[0] * invN;
    float var = rq[0] * invN - mean * mean;
    float sc = g1[o] * rsqrtf(var + EPSV);
    st1[o] = sc;
    st1[O + o] = b1[o] - mean * sc;
  }
}

// ---------------- finalize: pick max/min by scale sign, affine + leaky ----------------
__global__ void k_final(const float* __restrict__ st1, const float* __restrict__ zmin,
                        float* __restrict__ out) {
  int i = blockIdx.x * blockDim.x + threadIdx.x;
  if (i < Q * O) {
    int o = i & 63;
    float sc = st1[o], sh = st1[O + o];
    float base = (sc >= 0.f) ? out[i] : zmin[i];   // out currently holds zmax
    float v = base * sc + sh;
    out[i] = LEAKY(v);
  }
}

extern "C" void kernel_launch(void* const* d_in, const int* in_sizes, int n_in,
                              void* d_out, int out_size, void* d_ws, size_t ws_size,
                              hipStream_t stream) {
  const float* qpts = (const float*)d_in[0];
  const float* spts = (const float*)d_in[1];
  const float* feat = (const float*)d_in[2];
  const int*   inds = (const int*)d_in[3];
  const float* w0   = (const float*)d_in[4];
  const float* g0   = (const float*)d_in[5];
  const float* b0   = (const float*)d_in[6];
  const float* w1   = (const float*)d_in[7];
  const float* g1   = (const float*)d_in[8];
  const float* b1   = (const float*)d_in[9];
  float* out = (float*)d_out;

  char* ws = (char*)d_ws;
  int*   cnt  = (int*)(ws + CNT_OFF);
  float* p0   = (float*)(ws + P0_OFF);
  float* st0  = (float*)(ws + ST0_OFF);
  float* zmin = (float*)(ws + ZMIN_OFF);
  float* p1   = (float*)(ws + P1_OFF);
  float* st1  = (float*)(ws + ST1_OFF);
  short* w0f  = (short*)(ws + W0F_OFF);
  short* w1f  = (short*)(ws + W1F_OFF);

  hipMemsetAsync(cnt, 0, (size_t)S * sizeof(int), stream);
  k_prep<<<8, 256, 0, stream>>>(w0, w1, w0f, w1f);
  k_hist<<<512, 256, 0, stream>>>(inds, cnt);
  k_hsq<<<GH, 256, 0, stream>>>(feat, cnt, w0f, p0);
  k_stats0<<<1, 64, 0, stream>>>(p0, g0, b0, st0);
  k_main<<<GD, 256, 0, stream>>>(qpts, spts, feat, inds, w0f, w1f, st0, out, zmin, p1);
  k_red1<<<64, 256, 0, stream>>>(p1, g1, b1, st1);
  k_final<<<(Q * O) / 256, 256, 0, stream>>>(st1, zmin, out);
}